// Round 18
// baseline (118.947 us; speedup 1.0000x reference)
//
#include <hip/hip_runtime.h>
#include <stdint.h>

#define D_MODEL 1024
#define SEQ 2048
#define HALF 1024
#define K_EIG 24
#define GUARD4 24              // zero 16B-elements (8 rows each) before each slice = 192 rows
#define K4 128                 // real elements per slice (1024 rows / 8)
#define K4P (GUARD4 + K4)      // 152
#define WE_JP4 72              // 64 real + 8 zero (stage overrun)

typedef __attribute__((ext_vector_type(8))) short bf16x8;
typedef __attribute__((ext_vector_type(4))) float f32x4;
typedef _Float16 f16;
typedef _Float16 f16x2 __attribute__((ext_vector_type(2)));
typedef unsigned int uint;

#define GAS __attribute__((address_space(1)))
#define LAS __attribute__((address_space(3)))

static __device__ __forceinline__ unsigned short f2bf(float f) {
  union { float f; uint32_t u; } v; v.f = f;
  uint32_t u = v.u;
  u += 0x7FFFu + ((u >> 16) & 1u);
  return (unsigned short)(u >> 16);
}

static __device__ __forceinline__ float dot2(uint w2, uint u2, float c) {
  return __builtin_amdgcn_fdot2(__builtin_bit_cast(f16x2, w2),
                                __builtin_bit_cast(f16x2, u2), c, false);
}

static __device__ __forceinline__ uint pkrtz(float lo, float hi) {
  return __builtin_bit_cast(uint, __builtin_amdgcn_cvt_pkrtz(lo, hi));
}

static __device__ __forceinline__ uint pkbf(float lo, float hi) {
  return (uint)f2bf(lo) | ((uint)f2bf(hi) << 16);
}

// ------------- merged prep: [0,768) zero_guard | [768,1792) transpose_M | [1792,2080) we4 -------------
__global__ __launch_bounds__(256) void k_prep(const float* __restrict__ Mi,
                                              const float* __restrict__ phi,
                                              const float* __restrict__ Mf,
                                              uint4* __restrict__ u4,
                                              unsigned short* __restrict__ Mt,
                                              uint4* __restrict__ we4) {
  __shared__ float smem[1056];
  const int blk = (int)blockIdx.x;
  const int tidx = threadIdx.x;

  if (blk < 768) {
    int r = blk / 96;
    int idx = (blk - r * 96) * 256 + tidx;
    u4[(size_t)r * (K4P * 1024) + idx] = make_uint4(0u, 0u, 0u, 0u);
    return;
  }
  if (blk < 1792) {
    int bidx = blk - 768;
    int n0 = (bidx & 31) * 32, k0 = (bidx >> 5) * 32;
    float (*tile)[33] = (float(*)[33])smem;
    int tx = tidx & 31, ty = tidx >> 5;
    #pragma unroll
    for (int r = 0; r < 32; r += 8)
      tile[ty + r][tx] = Mi[(size_t)(k0 + ty + r) * D_MODEL + n0 + tx];
    __syncthreads();
    #pragma unroll
    for (int r = 0; r < 32; r += 8)
      Mt[(size_t)(n0 + ty + r) * D_MODEL + k0 + tx] = f2bf(tile[tx][ty + r]);
    return;
  }
  {
    int bidx = blk - 1792;
    int jp4 = bidx % 72;
    int d = (bidx / 72) * 256 + tidx;
    if (jp4 >= 64) {
      we4[(size_t)jp4 * D_MODEL + d] = make_uint4(0u, 0u, 0u, 0u);
      return;
    }
    float (*ph)[K_EIG] = (float(*)[K_EIG])smem;
    if (tidx < 8 * K_EIG) {
      int s = tidx / K_EIG, k = tidx - s * K_EIG;
      ph[s][k] = phi[(size_t)(16 * jp4 + 2 * s) * K_EIG + k];
    }
    __syncthreads();
    float s[8] = {};
    #pragma unroll
    for (int k = 0; k < K_EIG; ++k) {
      float mv = Mf[(size_t)k * D_MODEL + d];
      #pragma unroll
      for (int j = 0; j < 8; ++j) s[j] = fmaf(ph[j][k], mv, s[j]);
    }
    uint4 o;
    o.x = pkrtz(2.f * s[0], 2.f * s[1]);
    o.y = pkrtz(2.f * s[2], 2.f * s[3]);
    o.z = pkrtz(2.f * s[4], 2.f * s[5]);
    o.w = pkrtz(2.f * s[6], 2.f * s[7]);
    we4[(size_t)jp4 * D_MODEL + d] = o;
  }
}

// ------------- u = x @ M: fp32-A via global_load_lds, XOR-swizzled, 3-buffer counted-vmcnt pipeline -------------
__global__ __launch_bounds__(256) void k_gemm(const float* __restrict__ X,
                                              const unsigned short* __restrict__ Bt,
                                              uint* __restrict__ Ug) {
  __shared__ float Asf[3][128 * 32];           // 3 x 16KB
  __shared__ unsigned short Bs[3][128 * 32];   // 3 x 8KB
  const int bid = (int)blockIdx.x;             // 0..511
  const int swz = (bid & 7) * 64 + (bid >> 3); // XCD swizzle
  const int m0 = (swz >> 3) * 128;
  const int n0 = (swz & 7) * 128;
  const int tid = threadIdx.x;
  const int lane = tid & 63;
  const int wave = tid >> 6;
  const int wm = wave >> 1, wn = wave & 1;
  const int qo = lane >> 4;

  const int a_row = lane >> 3;
  const int a_chunk = (lane & 7) ^ a_row;         // A source chunk (floats a_chunk*4..+3)
  const int b_row = lane >> 2;
  const int b_chunk = (lane & 3) ^ (b_row & 3);   // B source chunk (bf16 b_chunk*8..+7)

#define GSTAGE(buf, k0v)                                                                  \
  {                                                                                       \
    float* abase = &Asf[buf][0];                                                          \
    unsigned short* bbase = &Bs[buf][0];                                                  \
    _Pragma("unroll") for (int c = 0; c < 4; ++c) {                                       \
      int rbase = wave * 32 + c * 8;                                                      \
      const float* srcA = X + (size_t)(m0 + rbase + a_row) * 1024 + (k0v) + a_chunk * 4;  \
      __builtin_amdgcn_global_load_lds((const GAS void*)srcA,                             \
                                       (LAS void*)(abase + rbase * 32), 16, 0, 0);        \
    }                                                                                     \
    _Pragma("unroll") for (int c = 0; c < 2; ++c) {                                       \
      int rbase = wave * 32 + c * 16;                                                     \
      const unsigned short* srcB = Bt + (size_t)(n0 + rbase + b_row) * 1024 + (k0v) + b_chunk * 8; \
      __builtin_amdgcn_global_load_lds((const GAS void*)srcB,                             \
                                       (LAS void*)(bbase + rbase * 32), 16, 0, 0);        \
    }                                                                                     \
  }

  f32x4 acc[4][4] = {};

  GSTAGE(0, 0);
  GSTAGE(1, 32);

  int cur = 0;    // t % 3
  int nx2 = 2;    // (t+2) % 3
#pragma unroll 1
  for (int t = 0; t < 32; ++t) {
    if (t < 31) {
      asm volatile("s_waitcnt vmcnt(6)" ::: "memory");   // my stage(t) complete
    } else {
      asm volatile("s_waitcnt vmcnt(0)" ::: "memory");   // last: drain all
    }
    __builtin_amdgcn_s_barrier();                        // all waves: stage(t) visible, compute(t-1) done
    asm volatile("" ::: "memory");
    if (t < 30) GSTAGE(nx2, (t + 2) * 32);               // WAR-safe after barrier

    bf16x8 a[4], b[4];
    const float* Acur = &Asf[cur][0];
    const unsigned short* Bcur = &Bs[cur][0];
    #pragma unroll
    for (int mt = 0; mt < 4; ++mt) {
      int m = wm * 64 + mt * 16 + (lane & 15);
      const float* base = Acur + m * 32;
      int s0 = (2 * qo) ^ (lane & 7);
      int s1 = s0 ^ 1;
      float4 f0 = *(const float4*)(base + s0 * 4);
      float4 f1 = *(const float4*)(base + s1 * 4);
      uint4 pk;
      pk.x = pkbf(f0.x, f0.y); pk.y = pkbf(f0.z, f0.w);
      pk.z = pkbf(f1.x, f1.y); pk.w = pkbf(f1.z, f1.w);
      a[mt] = __builtin_bit_cast(bf16x8, pk);
    }
    #pragma unroll
    for (int nt = 0; nt < 4; ++nt) {
      int n = wn * 64 + nt * 16 + (lane & 15);
      int sb = qo ^ (lane & 3);
      b[nt] = *(const bf16x8*)(Bcur + n * 32 + sb * 8);
    }
    #pragma unroll
    for (int mt = 0; mt < 4; ++mt)
      #pragma unroll
      for (int nt = 0; nt < 4; ++nt)
        acc[mt][nt] = __builtin_amdgcn_mfma_f32_16x16x32_bf16(a[mt], b[nt], acc[mt][nt], 0, 0, 0);

    cur = (cur == 2) ? 0 : cur + 1;
    nx2 = (nx2 == 2) ? 0 : nx2 + 1;
  }
#undef GSTAGE

  const int crow = (lane >> 4) * 4;
  const int ccol = lane & 15;
  #pragma unroll
  for (int mt = 0; mt < 4; ++mt) {
    int m = m0 + wm * 64 + mt * 16 + crow;
    int b_ = m >> 11;
    int t0 = m & 2047;
    int r_e = b_ << 1;
    int k4 = t0 >> 4;
    int dwo = (t0 >> 2) & 3;
    size_t base_e = ((size_t)(r_e * K4P + GUARD4 + k4) * 1024) * 4 + dwo;
    size_t base_o = ((size_t)((r_e + 1) * K4P + GUARD4 + k4) * 1024) * 4 + dwo;
    #pragma unroll
    for (int nt = 0; nt < 4; ++nt) {
      int n = n0 + wn * 64 + nt * 16 + ccol;
      Ug[base_e + (size_t)n * 4] = pkrtz(acc[mt][nt][0], acc[mt][nt][2]);
      Ug[base_o + (size_t)n * 4] = pkrtz(acc[mt][nt][1], acc[mt][nt][3]);
    }
  }
}

// ------------- depthwise causal conv: u ring in 32KB LDS, w in registers from L2 (ping-pong) -------------
// 512 thr = 64 d-lanes x 8 waves, 16 outputs/thread. LDS exactly 32KB -> 4-5 blocks/CU (32 waves).
__global__ __launch_bounds__(512, 8) void k_conv(const uint4* __restrict__ u4,
                                                 const uint4* __restrict__ we4,
                                                 float* __restrict__ out) {
  __shared__ uint4 u_r[32 * 64];     // 32KB ring: [k4 & 31][dl], element = 4 pairs = 8 rows
  const int flat = blockIdx.x;       // 0..1023
  const int dt = flat & 15;          // flat&7 pins d-column to one XCD
  const int r  = (flat >> 4) & 7;
  const int a  = 7 - (flat >> 7);    // heavy tiles dispatched first
  const int d0 = dt * 64;
  const int tid = threadIdx.x;
  const int dl = tid & 63;
  const int ig = tid >> 6;           // wave 0..7

  const uint4* ub = u4 + ((size_t)r * K4P + GUARD4) * 1024 + d0;   // + k4*1024 + dl
  const uint4* wb = we4 + d0 + dl;                                 // + row*1024
  const int b_ = r >> 1, p = r & 1;

#define STAGEU(k40)                                                                     \
  {                                                                                     \
    int k4e = (k40) + ig;                                                               \
    const uint4* src = ub + (long long)k4e * 1024 + dl;                                 \
    __builtin_amdgcn_global_load_lds((const GAS void*)src,                              \
                                     (LAS void*)(u_r + (k4e & 31) * 64), 16, 0, 0);     \
  }

  // 16-tap sub-block: u elements kb..kb+3 from ring, w pair (wv0, wv1) from registers
#define DOTS(kb_, wv0, wv1)                                                             \
  {                                                                                     \
    const int kb = (kb_);                                                               \
    uint4 v0 = u_r[((kb + 0) & 31) * 64 + dl];                                          \
    uint4 v1 = u_r[((kb + 1) & 31) * 64 + dl];                                          \
    uint4 v2 = u_r[((kb + 2) & 31) * 64 + dl];                                          \
    uint4 v3 = u_r[((kb + 3) & 31) * 64 + dl];                                          \
    uint P[16];                                                                         \
    P[0] = v0.x; P[1] = v0.y; P[2] = v0.z; P[3] = v0.w;                                 \
    P[4] = v1.x; P[5] = v1.y; P[6] = v1.z; P[7] = v1.w;                                 \
    P[8] = v2.x; P[9] = v2.y; P[10] = v2.z; P[11] = v2.w;                               \
    P[12] = v3.x; P[13] = v3.y; P[14] = v3.z; P[15] = v3.w;                             \
    uint W[8];                                                                          \
    W[0] = (wv0).x; W[1] = (wv0).y; W[2] = (wv0).z; W[3] = (wv0).w;                     \
    W[4] = (wv1).x; W[5] = (wv1).y; W[6] = (wv1).z; W[7] = (wv1).w;                     \
    uint WS[8];                                                                         \
    _Pragma("unroll") for (int q = 0; q < 8; ++q)                                       \
      WS[q] = __builtin_amdgcn_alignbit(W[q], W[q], 16);                                \
    uint pe[15];                                                                        \
    _Pragma("unroll") for (int j = 0; j < 15; ++j)                                      \
      pe[j] = __builtin_amdgcn_perm(P[j + 1], P[j], 0x03020504u);                       \
    _Pragma("unroll") for (int q = 0; q < 8; ++q) {                                     \
      _Pragma("unroll") for (int h = 0; h < 8; ++h) {                                   \
        acc[2 * h]     = dot2(W[q],  pe[7 - q + h], acc[2 * h]);                        \
        acc[2 * h + 1] = dot2(WS[q], P[8 - q + h],  acc[2 * h + 1]);                    \
      }                                                                                 \
    }                                                                                   \
  }

  const int i0 = a * 128;
  const int ibase = i0 + ig * 16;
  const int niter = (2 * a + 2) < 8 ? (2 * a + 2) : 8;   // zero-tap chunks skipped

  STAGEU(16 * a - 8); STAGEU(16 * a); STAGEU(16 * a + 8);
  __syncthreads();

  float acc[16];
#pragma unroll
  for (int o = 0; o < 16; ++o) acc[o] = 0.f;

  // w ping-pong registers: chunk c sub-block s uses rows 8c+2s, 8c+2s+1 (max row 65 < 72)
  uint4 wA0 = wb[0], wA1 = wb[1024];       // chunk 0, s=0
  uint4 wB0, wB1;

#pragma unroll 1
  for (int c = 0; c < niter; ++c) {
    STAGEU(16 * a - 8 * c - 16);           // u elements for chunk c+1 (disjoint slots)
    const int kbase = 16 * a + 2 * ig - 8 * c - 2;
    wB0 = wb[(size_t)(8 * c + 2) * 1024]; wB1 = wb[(size_t)(8 * c + 3) * 1024];
    DOTS(kbase - 0, wA0, wA1);             // s=0 (covers wB load)
    wA0 = wb[(size_t)(8 * c + 4) * 1024]; wA1 = wb[(size_t)(8 * c + 5) * 1024];
    DOTS(kbase - 2, wB0, wB1);             // s=1
    wB0 = wb[(size_t)(8 * c + 6) * 1024]; wB1 = wb[(size_t)(8 * c + 7) * 1024];
    DOTS(kbase - 4, wA0, wA1);             // s=2
    wA0 = wb[(size_t)(8 * c + 8) * 1024]; wA1 = wb[(size_t)(8 * c + 9) * 1024];
    DOTS(kbase - 6, wB0, wB1);             // s=3 (wA now holds next chunk's s=0)
    __syncthreads();
  }

#pragma unroll
  for (int o = 0; o < 16; ++o)
    out[((size_t)b_ * SEQ + 2 * (ibase + o) + p) * D_MODEL + d0 + dl] = acc[o];
#undef STAGEU
#undef DOTS
}

extern "C" void kernel_launch(void* const* d_in, const int* in_sizes, int n_in,
                              void* d_out, int out_size, void* d_ws, size_t ws_size,
                              hipStream_t stream) {
  const float* x   = (const float*)d_in[0];   // [4][2048][1024]
  const float* Mi  = (const float*)d_in[1];   // [1024][1024]
  const float* Mf  = (const float*)d_in[2];   // [24][1024]
  const float* phi = (const float*)d_in[3];   // [2048][24]
  float* out = (float*)d_out;

  // Mt (2MB) lives in d_out -- dead before conv writes out.
  unsigned short* Mt = (unsigned short*)d_out;

  char* ws = (char*)d_ws;
  uint4* we4 = (uint4*)(ws);                   // 72*1024*16B = 1.18 MB
  uint4* u4  = (uint4*)(ws + (2u << 20));      // 8*152*1024*16B = 19.9 MB

  hipLaunchKernelGGL(k_prep, dim3(2080), dim3(256), 0, stream, Mi, phi, Mf, u4, Mt, we4);
  hipLaunchKernelGGL(k_gemm, dim3(512), dim3(256), 0, stream, x, Mt, (uint*)u4);
  hipLaunchKernelGGL(k_conv, dim3(1024), dim3(512), 0, stream, u4, we4, out);
}

// Round 19
// 114.352 us; speedup vs baseline: 1.0402x; 1.0402x over previous
//
#include <hip/hip_runtime.h>
#include <stdint.h>

#define D_MODEL 1024
#define SEQ 2048
#define HALF 1024
#define K_EIG 24
#define GUARD4 24              // zero 16B-elements (8 rows each) before each slice = 192 rows
#define K4 128                 // real elements per slice (1024 rows / 8)
#define K4P (GUARD4 + K4)      // 152
#define WE_JP4 72              // 64 real + 8 zero (stage overrun)

typedef __attribute__((ext_vector_type(8))) short bf16x8;
typedef __attribute__((ext_vector_type(4))) float f32x4;
typedef _Float16 f16;
typedef _Float16 f16x2 __attribute__((ext_vector_type(2)));
typedef unsigned int uint;

#define GAS __attribute__((address_space(1)))
#define LAS __attribute__((address_space(3)))

static __device__ __forceinline__ unsigned short f2bf(float f) {
  union { float f; uint32_t u; } v; v.f = f;
  uint32_t u = v.u;
  u += 0x7FFFu + ((u >> 16) & 1u);
  return (unsigned short)(u >> 16);
}

static __device__ __forceinline__ float dot2(uint w2, uint u2, float c) {
  return __builtin_amdgcn_fdot2(__builtin_bit_cast(f16x2, w2),
                                __builtin_bit_cast(f16x2, u2), c, false);
}

static __device__ __forceinline__ uint pkrtz(float lo, float hi) {
  return __builtin_bit_cast(uint, __builtin_amdgcn_cvt_pkrtz(lo, hi));
}

// ------------- merged prep: [0,8192) x->bf16 | [8192,8960) zero_guard | [8960,9984) transpose_M
//               | [9984,10272) we4 -------------
__global__ __launch_bounds__(256) void k_prep(const float* __restrict__ X,
                                              const float* __restrict__ Mi,
                                              const float* __restrict__ phi,
                                              const float* __restrict__ Mf,
                                              uint4* __restrict__ u4,
                                              unsigned short* __restrict__ x_bf,
                                              unsigned short* __restrict__ Mt,
                                              uint4* __restrict__ we4) {
  __shared__ float smem[1056];
  const int blk = (int)blockIdx.x;
  const int tidx = threadIdx.x;

  if (blk < 8192) {
    // convert x: 2M float4
    int idx = blk * 256 + tidx;
    float4 v = ((const float4*)X)[idx];
    ushort4 o;
    o.x = f2bf(v.x); o.y = f2bf(v.y); o.z = f2bf(v.z); o.w = f2bf(v.w);
    ((ushort4*)x_bf)[idx] = o;
    return;
  }
  if (blk < 8960) {
    int b2 = blk - 8192;
    int r = b2 / 96;
    int idx = (b2 - r * 96) * 256 + tidx;
    u4[(size_t)r * (K4P * 1024) + idx] = make_uint4(0u, 0u, 0u, 0u);
    return;
  }
  if (blk < 9984) {
    int bidx = blk - 8960;
    int n0 = (bidx & 31) * 32, k0 = (bidx >> 5) * 32;
    float (*tile)[33] = (float(*)[33])smem;
    int tx = tidx & 31, ty = tidx >> 5;
    #pragma unroll
    for (int r = 0; r < 32; r += 8)
      tile[ty + r][tx] = Mi[(size_t)(k0 + ty + r) * D_MODEL + n0 + tx];
    __syncthreads();
    #pragma unroll
    for (int r = 0; r < 32; r += 8)
      Mt[(size_t)(n0 + ty + r) * D_MODEL + k0 + tx] = f2bf(tile[tx][ty + r]);
    return;
  }
  {
    int bidx = blk - 9984;
    int jp4 = bidx % 72;
    int d = (bidx / 72) * 256 + tidx;
    if (jp4 >= 64) {
      we4[(size_t)jp4 * D_MODEL + d] = make_uint4(0u, 0u, 0u, 0u);
      return;
    }
    float (*ph)[K_EIG] = (float(*)[K_EIG])smem;
    if (tidx < 8 * K_EIG) {
      int s = tidx / K_EIG, k = tidx - s * K_EIG;
      ph[s][k] = phi[(size_t)(16 * jp4 + 2 * s) * K_EIG + k];
    }
    __syncthreads();
    float s[8] = {};
    #pragma unroll
    for (int k = 0; k < K_EIG; ++k) {
      float mv = Mf[(size_t)k * D_MODEL + d];
      #pragma unroll
      for (int j = 0; j < 8; ++j) s[j] = fmaf(ph[j][k], mv, s[j]);
    }
    uint4 o;
    o.x = pkrtz(2.f * s[0], 2.f * s[1]);
    o.y = pkrtz(2.f * s[2], 2.f * s[3]);
    o.z = pkrtz(2.f * s[4], 2.f * s[5]);
    o.w = pkrtz(2.f * s[6], 2.f * s[7]);
    we4[(size_t)jp4 * D_MODEL + d] = o;
  }
}

// ------------- u = x_bf @ Mt^T (bf16 MFMA), A/B both bf16 via global_load_lds, XOR-swizzled, dbuf -------------
// LDS: ushort[128][32] per operand per buffer; chunk c of row r stored at slot c ^ (r&3). 32KB total
// -> 5 blocks/CU. Stage(t+1) issued before compute(t); one barrier per K-step.
__global__ __launch_bounds__(256) void k_gemm(const unsigned short* __restrict__ A,
                                              const unsigned short* __restrict__ Bt,
                                              uint* __restrict__ Ug) {
  __shared__ unsigned short As[2][128 * 32];   // 2 x 8KB
  __shared__ unsigned short Bs[2][128 * 32];   // 2 x 8KB
  const int bid = (int)blockIdx.x;             // 0..511
  const int swz = (bid & 7) * 64 + (bid >> 3); // XCD swizzle
  const int m0 = (swz >> 3) * 128;
  const int n0 = (swz & 7) * 128;
  const int tid = threadIdx.x;
  const int lane = tid & 63;
  const int wave = tid >> 6;
  const int wm = wave >> 1, wn = wave & 1;
  const int qo = lane >> 4;

  const int row_ = lane >> 2;                     // 16 rows per stage inst
  const int chunk_ = (lane & 3) ^ (row_ & 3);     // source chunk (bf16 chunk_*8..+7)

#define GSTAGE(buf, k0v)                                                                  \
  {                                                                                       \
    _Pragma("unroll") for (int c = 0; c < 2; ++c) {                                       \
      int rbase = wave * 32 + c * 16;                                                     \
      const unsigned short* srcA = A + (size_t)(m0 + rbase + row_) * 1024 + (k0v) + chunk_ * 8; \
      __builtin_amdgcn_global_load_lds((const GAS void*)srcA,                             \
                                       (LAS void*)(&As[buf][0] + rbase * 32), 16, 0, 0);  \
      const unsigned short* srcB = Bt + (size_t)(n0 + rbase + row_) * 1024 + (k0v) + chunk_ * 8; \
      __builtin_amdgcn_global_load_lds((const GAS void*)srcB,                             \
                                       (LAS void*)(&Bs[buf][0] + rbase * 32), 16, 0, 0);  \
    }                                                                                     \
  }

  f32x4 acc[4][4] = {};

  GSTAGE(0, 0);
  __syncthreads();

#pragma unroll 1
  for (int t = 0; t < 32; ++t) {
    const int cur = t & 1;
    if (t < 31) GSTAGE(cur ^ 1, (t + 1) * 32);

    const int sa = qo ^ (lane & 3);              // slot of chunk qo for row with m&3 == lane&3
    bf16x8 a[4], b[4];
    #pragma unroll
    for (int mt = 0; mt < 4; ++mt)
      a[mt] = *(const bf16x8*)(&As[cur][0] + (wm * 64 + mt * 16 + (lane & 15)) * 32 + sa * 8);
    #pragma unroll
    for (int nt = 0; nt < 4; ++nt)
      b[nt] = *(const bf16x8*)(&Bs[cur][0] + (wn * 64 + nt * 16 + (lane & 15)) * 32 + sa * 8);
    #pragma unroll
    for (int mt = 0; mt < 4; ++mt)
      #pragma unroll
      for (int nt = 0; nt < 4; ++nt)
        acc[mt][nt] = __builtin_amdgcn_mfma_f32_16x16x32_bf16(a[mt], b[nt], acc[mt][nt], 0, 0, 0);

    __syncthreads();   // stage(t+1) drain covered by compute; WAR protection
  }
#undef GSTAGE

  // epilogue: quad q -> t = t0+q. q0,q2 -> slice r_e rows i,i+1; q1,q3 -> r_o.
  const int crow = (lane >> 4) * 4;
  const int ccol = lane & 15;
  #pragma unroll
  for (int mt = 0; mt < 4; ++mt) {
    int m = m0 + wm * 64 + mt * 16 + crow;
    int b_ = m >> 11;
    int t0 = m & 2047;
    int r_e = b_ << 1;
    int k4 = t0 >> 4;
    int dwo = (t0 >> 2) & 3;
    size_t base_e = ((size_t)(r_e * K4P + GUARD4 + k4) * 1024) * 4 + dwo;
    size_t base_o = ((size_t)((r_e + 1) * K4P + GUARD4 + k4) * 1024) * 4 + dwo;
    #pragma unroll
    for (int nt = 0; nt < 4; ++nt) {
      int n = n0 + wn * 64 + nt * 16 + ccol;
      Ug[base_e + (size_t)n * 4] = pkrtz(acc[mt][nt][0], acc[mt][nt][2]);
      Ug[base_o + (size_t)n * 4] = pkrtz(acc[mt][nt][1], acc[mt][nt][3]);
    }
  }
}

// ------------- depthwise causal conv: u ring in 32KB LDS, w in registers from L2 (R18 proven) -------------
__global__ __launch_bounds__(512, 8) void k_conv(const uint4* __restrict__ u4,
                                                 const uint4* __restrict__ we4,
                                                 float* __restrict__ out) {
  __shared__ uint4 u_r[32 * 64];     // 32KB ring: [k4 & 31][dl], element = 4 pairs = 8 rows
  const int flat = blockIdx.x;       // 0..1023
  const int dt = flat & 15;          // flat&7 pins d-column to one XCD
  const int r  = (flat >> 4) & 7;
  const int a  = 7 - (flat >> 7);    // heavy tiles dispatched first
  const int d0 = dt * 64;
  const int tid = threadIdx.x;
  const int dl = tid & 63;
  const int ig = tid >> 6;           // wave 0..7

  const uint4* ub = u4 + ((size_t)r * K4P + GUARD4) * 1024 + d0;   // + k4*1024 + dl
  const uint4* wb = we4 + d0 + dl;                                 // + row*1024
  const int b_ = r >> 1, p = r & 1;

#define STAGEU(k40)                                                                     \
  {                                                                                     \
    int k4e = (k40) + ig;                                                               \
    const uint4* src = ub + (long long)k4e * 1024 + dl;                                 \
    __builtin_amdgcn_global_load_lds((const GAS void*)src,                              \
                                     (LAS void*)(u_r + (k4e & 31) * 64), 16, 0, 0);     \
  }

#define DOTS(kb_, wv0, wv1)                                                             \
  {                                                                                     \
    const int kb = (kb_);                                                               \
    uint4 v0 = u_r[((kb + 0) & 31) * 64 + dl];                                          \
    uint4 v1 = u_r[((kb + 1) & 31) * 64 + dl];                                          \
    uint4 v2 = u_r[((kb + 2) & 31) * 64 + dl];                                          \
    uint4 v3 = u_r[((kb + 3) & 31) * 64 + dl];                                          \
    uint P[16];                                                                         \
    P[0] = v0.x; P[1] = v0.y; P[2] = v0.z; P[3] = v0.w;                                 \
    P[4] = v1.x; P[5] = v1.y; P[6] = v1.z; P[7] = v1.w;                                 \
    P[8] = v2.x; P[9] = v2.y; P[10] = v2.z; P[11] = v2.w;                               \
    P[12] = v3.x; P[13] = v3.y; P[14] = v3.z; P[15] = v3.w;                             \
    uint W[8];                                                                          \
    W[0] = (wv0).x; W[1] = (wv0).y; W[2] = (wv0).z; W[3] = (wv0).w;                     \
    W[4] = (wv1).x; W[5] = (wv1).y; W[6] = (wv1).z; W[7] = (wv1).w;                     \
    uint WS[8];                                                                         \
    _Pragma("unroll") for (int q = 0; q < 8; ++q)                                       \
      WS[q] = __builtin_amdgcn_alignbit(W[q], W[q], 16);                                \
    uint pe[15];                                                                        \
    _Pragma("unroll") for (int j = 0; j < 15; ++j)                                      \
      pe[j] = __builtin_amdgcn_perm(P[j + 1], P[j], 0x03020504u);                       \
    _Pragma("unroll") for (int q = 0; q < 8; ++q) {                                     \
      _Pragma("unroll") for (int h = 0; h < 8; ++h) {                                   \
        acc[2 * h]     = dot2(W[q],  pe[7 - q + h], acc[2 * h]);                        \
        acc[2 * h + 1] = dot2(WS[q], P[8 - q + h],  acc[2 * h + 1]);                    \
      }                                                                                 \
    }                                                                                   \
  }

  const int i0 = a * 128;
  const int ibase = i0 + ig * 16;
  const int niter = (2 * a + 2) < 8 ? (2 * a + 2) : 8;   // zero-tap chunks skipped

  STAGEU(16 * a - 8); STAGEU(16 * a); STAGEU(16 * a + 8);
  __syncthreads();

  float acc[16];
#pragma unroll
  for (int o = 0; o < 16; ++o) acc[o] = 0.f;

  uint4 wA0 = wb[0], wA1 = wb[1024];       // chunk 0, s=0
  uint4 wB0, wB1;

#pragma unroll 1
  for (int c = 0; c < niter; ++c) {
    STAGEU(16 * a - 8 * c - 16);           // u elements for chunk c+1 (disjoint slots)
    const int kbase = 16 * a + 2 * ig - 8 * c - 2;
    wB0 = wb[(size_t)(8 * c + 2) * 1024]; wB1 = wb[(size_t)(8 * c + 3) * 1024];
    DOTS(kbase - 0, wA0, wA1);             // s=0
    wA0 = wb[(size_t)(8 * c + 4) * 1024]; wA1 = wb[(size_t)(8 * c + 5) * 1024];
    DOTS(kbase - 2, wB0, wB1);             // s=1
    wB0 = wb[(size_t)(8 * c + 6) * 1024]; wB1 = wb[(size_t)(8 * c + 7) * 1024];
    DOTS(kbase - 4, wA0, wA1);             // s=2
    wA0 = wb[(size_t)(8 * c + 8) * 1024]; wA1 = wb[(size_t)(8 * c + 9) * 1024];
    DOTS(kbase - 6, wB0, wB1);             // s=3
    __syncthreads();
  }

#pragma unroll
  for (int o = 0; o < 16; ++o)
    out[((size_t)b_ * SEQ + 2 * (ibase + o) + p) * D_MODEL + d0 + dl] = acc[o];
#undef STAGEU
#undef DOTS
}

extern "C" void kernel_launch(void* const* d_in, const int* in_sizes, int n_in,
                              void* d_out, int out_size, void* d_ws, size_t ws_size,
                              hipStream_t stream) {
  const float* x   = (const float*)d_in[0];   // [4][2048][1024]
  const float* Mi  = (const float*)d_in[1];   // [1024][1024]
  const float* Mf  = (const float*)d_in[2];   // [24][1024]
  const float* phi = (const float*)d_in[3];   // [2048][24]
  float* out = (float*)d_out;

  // x_bf (16MB) and Mt (2MB) live in d_out -- dead before conv writes out.
  unsigned short* x_bf = (unsigned short*)d_out;
  unsigned short* Mt   = (unsigned short*)((char*)d_out + (16u << 20));

  char* ws = (char*)d_ws;
  uint4* we4 = (uint4*)(ws);                   // 72*1024*16B = 1.18 MB
  uint4* u4  = (uint4*)(ws + (2u << 20));      // 8*152*1024*16B = 19.9 MB

  hipLaunchKernelGGL(k_prep, dim3(10272), dim3(256), 0, stream, x, Mi, phi, Mf, u4, x_bf, Mt, we4);
  hipLaunchKernelGGL(k_gemm, dim3(512), dim3(256), 0, stream, x_bf, Mt, (uint*)u4);
  hipLaunchKernelGGL(k_conv, dim3(1024), dim3(512), 0, stream, u4, we4, out);
}